// Round 1
// baseline (5270.200 us; speedup 1.0000x reference)
//
#include <hip/hip_runtime.h>
#include <hip/hip_fp16.h>

#define S 31
#define D 14
#define H 50
#define NB 16384
#define NITER 48
#define LAMR 1e-4f

// ws float-index layout (hx lives in LDS only; layout unchanged otherwise)
#define WS_D2   0      // 48: global sum ||F-X||^2 per iter
#define WS_F2   64     // 48: global sum ||F||^2 per iter
#define WS_WHP  128    // 50x16 fp32 Wh (padded)
#define WS_BHX  928    // 64: bh+bx fp32
#define WS_BO   992    // 16: bo fp32
#define WS_WX2  1024   // 50x8 half2: Wx rows packed (d pairs)
#define WS_WO2  1424   // 14x26 half2: Wo rows packed (h pairs)
#define WS_WF2  1792   // 32x8 half2: Wf per-s slices (row 31 = 0)
#define WS_OUTK 4096   // 48*NB floats

typedef _Float16 f16x2 __attribute__((ext_vector_type(2)));

#if defined(__has_builtin) && __has_builtin(__builtin_amdgcn_rcpf)
#define FRCP(x) __builtin_amdgcn_rcpf(x)
#else
#define FRCP(x) (1.0f/(x))
#endif

#if defined(__has_builtin) && __has_builtin(__builtin_amdgcn_exp2f)
#define FEXP2(x) __builtin_amdgcn_exp2f(x)
#else
#define FEXP2(x) exp2f(x)
#endif

#define FDOT2(a,b,c) __builtin_amdgcn_fdot2((a),(b),(c),false)

__device__ __forceinline__ f16x2 pkrtz(float a, float b){
  auto r = __builtin_amdgcn_cvt_pkrtz(a, b);
  return __builtin_bit_cast(f16x2, r);
}
#define PKRTZ(a,b) pkrtz((a),(b))

__device__ __forceinline__ f16x2 pack_rn(float a, float b){
  __half2 h = __floats2half2_rn(a, b);
  return __builtin_bit_cast(f16x2, h);
}

// triangular index, i<=j, 6x6
#define AIJ(i,j) ((i)*6 - ((i)*((i)+1))/2 + (j))

__device__ __forceinline__ float tfast(float x){
  // tanh(x) = 1 - 2/(exp2(x*2*log2e)+1): v_mul + v_exp + v_add + v_rcp + v_fma
  float e = FEXP2(x * 2.8853900817779268f);
  return 1.f - 2.f * FRCP(e + 1.f);
}

__device__ __forceinline__ float half_red(float v){
  v += __shfl_xor(v, 1);
  v += __shfl_xor(v, 2);
  v += __shfl_xor(v, 4);
  v += __shfl_xor(v, 8);
  v += __shfl_xor(v, 16);
  return v;   // sum over 32-lane half
}

__global__ void prep_kernel(const float* __restrict__ Wh, const float* __restrict__ bh,
                            const float* __restrict__ Wx, const float* __restrict__ bx,
                            const float* __restrict__ Wo, const float* __restrict__ bo,
                            const float* __restrict__ Wf, float* __restrict__ ws){
  int t = threadIdx.x;                       // 1 block x 256
  for (int i=t;i<128;i+=256) ws[i]=0.f;      // zero norm accumulators
  for (int i=t;i<800;i+=256){
    int h=i>>4, d=i&15;
    ws[WS_WHP+i] = (d<D)? Wh[h*D+d] : 0.f;
  }
  for (int i=t;i<64;i+=256) ws[WS_BHX+i] = (i<H)? bh[i]+bx[i] : 0.f;
  for (int i=t;i<16;i+=256) ws[WS_BO+i]  = (i<D)? bo[i] : 0.f;
  __half2* wx2 = (__half2*)(ws + WS_WX2);
  for (int i=t;i<400;i+=256){
    int h=i>>3, dd=i&7, d0=2*dd, d1=2*dd+1;
    float a=(d0<D)?Wx[h*D+d0]:0.f, b=(d1<D)?Wx[h*D+d1]:0.f;
    wx2[i] = __floats2half2_rn(a,b);
  }
  __half2* wo2 = (__half2*)(ws + WS_WO2);
  for (int i=t;i<364;i+=256){
    int d=i/26, hh=i-26*d, h0=2*hh, h1=2*hh+1;
    float a=(hh<25)?Wo[d*H+h0]:0.f, b=(hh<25)?Wo[d*H+h1]:0.f;
    wo2[i] = __floats2half2_rn(a,b);
  }
  __half2* wf2 = (__half2*)(ws + WS_WF2);
  for (int i=t;i<256;i+=256){
    int s=i>>3, dd=i&7, d0=2*dd, d1=2*dd+1;
    float a=(s<S && d0<D)?Wf[s*D+d0]:0.f, b=(s<S && d1<D)?Wf[s*D+d1]:0.f;
    wf2[i] = __floats2half2_rn(a,b);
  }
}

// f-eval, fused layers: per h-pair compute layer-1 dot + tanh, immediately
// accumulate into the 14 layer-2 fp32 chains (no thh[25] staging array).
#define FEVAL() do{ \
  float oacc_[14]; \
  _Pragma("unroll") for (int d_=0; d_<14; ++d_) oacc_[d_] = bop[d_]; \
  _Pragma("unroll") \
  for (int hh_=0; hh_<25; ++hh_){ \
    f16x2 hx2_ = hxr2[hh_]; \
    float a0_ = (float)hx2_[0], b0_ = (float)hx2_[1]; \
    _Pragma("unroll") for (int q_=0;q_<7;++q_){ \
      a0_ = FDOT2(xvh[q_], wx2[(2*hh_)*8+q_],   a0_); \
      b0_ = FDOT2(xvh[q_], wx2[(2*hh_+1)*8+q_], b0_); } \
    f16x2 th_ = PKRTZ(tfast(a0_), tfast(b0_)); \
    _Pragma("unroll") for (int d_=0; d_<14; ++d_) \
      oacc_[d_] = FDOT2(th_, wo2[d_*26+hh_], oacc_[d_]); \
  } \
  _Pragma("unroll") for (int dp_=0; dp_<7; ++dp_) \
    fvh[dp_] = PKRTZ(tfast(oacc_[2*dp_]), tfast(oacc_[2*dp_+1])); \
}while(0)

#define ZERO_INACT() do{ \
  if (!act){ \
    _Pragma("unroll") for (int q_=0;q_<7;++q_){ fvh[q_]=zzv; gvh[q_]=zzv; } \
  } \
}while(0)

// Overwrite history slot C in place (permutation-invariant Anderson):
// all indices compile-time constants -> no shift movs, no scratch.
#define PUSH_SLOT(C) do{ \
  _Pragma("unroll") for (int q_=0;q_<7;++q_){ Fh[(C)*7+q_]=fvh[q_]; Gh[(C)*7+q_]=gvh[q_]; } \
  _Pragma("unroll") for (int j_=0;j_<6;++j_){ \
    if (j_ != (C)) GG[ (j_<(C)) ? AIJ(j_,(C)) : AIJ((C),j_) ] = dnr_[j_]; } \
  GG[AIJ((C),(C))] = d2r; \
}while(0)

#define PUSH(SLOT_) do{ \
  float dnr_[6]; \
  _Pragma("unroll") for (int j_=0;j_<6;++j_){ \
    float acc_=0.f; \
    _Pragma("unroll") for (int q_=0;q_<7;++q_) acc_ = FDOT2(gvh[q_], Gh[j_*7+q_], acc_); \
    dnr_[j_] = half_red(acc_); } \
  d2l=0.f; f2l=0.f; \
  _Pragma("unroll") for (int q_=0;q_<7;++q_){ \
    d2l = FDOT2(gvh[q_], gvh[q_], d2l); \
    f2l = FDOT2(fvh[q_], fvh[q_], f2l); } \
  d2r = half_red(d2l); f2r = half_red(f2l); \
  switch(SLOT_){ \
    case 0: PUSH_SLOT(0); break; \
    case 1: PUSH_SLOT(1); break; \
    case 2: PUSH_SLOT(2); break; \
    case 3: PUSH_SLOT(3); break; \
    case 4: PUSH_SLOT(4); break; \
    default: PUSH_SLOT(5); break; } \
}while(0)

__global__ __launch_bounds__(256, 3)
void solver_kernel(const float* __restrict__ x,
                   const float* __restrict__ whp, const float* __restrict__ bhx,
                   const float* __restrict__ bop,
                   const f16x2* __restrict__ wx2, const f16x2* __restrict__ wo2,
                   const f16x2* __restrict__ wf2,
                   float* __restrict__ outk, float* __restrict__ d2p, float* __restrict__ f2p){
  const int tid  = threadIdx.x;
  const int lane = tid & 63;
  const int s    = tid & 31;
  const int elem = blockIdx.x*8 + (tid>>5);
  const bool act = (s < S);

  // hx as f16x2, stride 27 words (odd -> all-bank spread, 2-way max = free)
  __shared__ f16x2 hx2_sh[256*27];          // 27648 B (was 52224)
  f16x2* hxw2 = hx2_sh + tid*27;

  { // prologue: hx[h] = x_s . Wh_h + bh_h + bx_h  (exact fp32, one RNE round)
    float xd[D];
#pragma unroll
    for (int d=0; d<D; ++d) xd[d]=0.f;
    if (act){
      const float* xr = x + ((size_t)elem*S + s)*D;
#pragma unroll
      for (int d=0; d<D; ++d) xd[d]=xr[d];
    }
#pragma unroll 5
    for (int hp=0; hp<25; ++hp){
      float a0 = bhx[2*hp], a1 = bhx[2*hp+1];
#pragma unroll
      for (int d=0; d<D; ++d){
        a0 += xd[d]*whp[(2*hp)*16+d];
        a1 += xd[d]*whp[(2*hp+1)*16+d];
      }
      hxw2[hp] = pack_rn(a0, a1);
    }
  }
  const f16x2* hxr2 = hxw2;
  const f16x2 zzv = {(_Float16)0.f, (_Float16)0.f};

  f16x2 Fh[42], Gh[42], xvh[7], fvh[7], gvh[7];
  float GG[21];
  float d2l, f2l, d2r, f2r;
#pragma unroll
  for (int i=0;i<42;++i){ Fh[i]=zzv; Gh[i]=zzv; }
#pragma unroll
  for (int i=0;i<21;++i) GG[i]=0.f;

  int slot = 0;
#pragma unroll 1
  for (int kk=0; kk<50; ++kk){
    if (kk == 0){
#pragma unroll
      for (int q=0;q<7;++q) xvh[q]=zzv;
    } else if (kk == 1){
#pragma unroll
      for (int q=0;q<7;++q) xvh[q]=fvh[q];      // X1 = F0
    } else {
      float A_[21], invd[6], yv[6];
      if (kk >= 6){
#pragma unroll
        for (int i=0;i<6;++i)
#pragma unroll
          for (int j=i;j<6;++j) A_[AIJ(i,j)] = GG[AIJ(i,j)] + ((i==j)?LAMR:0.f);
      } else {
        // slots 0..kk-1 valid (filled in order); mask the rest with big diag
#pragma unroll
        for (int i=0;i<6;++i)
#pragma unroll
          for (int j=i;j<6;++j){
            float v = GG[AIJ(i,j)] + ((i==j)?LAMR:0.f);
            A_[AIJ(i,j)] = (j < kk)? v : ((i==j)?1e30f:0.f);
          }
      }
#pragma unroll
      for (int i=0;i<6;++i) yv[i]=1.f;
      // symmetric GE (no pivoting; SPD + big-diag pads)
#pragma unroll
      for (int p=0;p<6;++p){
        invd[p] = FRCP(A_[AIJ(p,p)]);
#pragma unroll
        for (int i=p+1;i<6;++i){
          float m = A_[AIJ(p,i)]*invd[p];
#pragma unroll
          for (int j=i;j<6;++j) A_[AIJ(i,j)] -= m*A_[AIJ(p,j)];
          yv[i] -= m*yv[p];
        }
      }
#pragma unroll
      for (int p=5;p>=0;--p){
        float acc=yv[p];
#pragma unroll
        for (int j=p+1;j<6;++j) acc -= A_[AIJ(p,j)]*yv[j];
        yv[p]=acc*invd[p];
      }
      float isum = FRCP(yv[0]+yv[1]+yv[2]+yv[3]+yv[4]+yv[5]);
      // Xk = sum_j alpha_j F_j (absolute slots; invalid slots have F=0, alpha~0)
#pragma unroll
      for (int q=0;q<7;++q) xvh[q]=zzv;
#pragma unroll
      for (int j=0;j<6;++j){
        _Float16 ah = (_Float16)(yv[j]*isum);
        f16x2 a2 = {ah, ah};
#pragma unroll
        for (int q=0;q<7;++q) xvh[q] += a2*Fh[j*7+q];
      }
    }
    FEVAL();
#pragma unroll
    for (int q=0;q<7;++q) gvh[q]=fvh[q]-xvh[q];
    ZERO_INACT();
    PUSH(slot);
    if (kk >= 2){
      // projection through Wf for this iterate
      float po=0.f;
      const f16x2* wfr = wf2 + s*8;
#pragma unroll
      for (int q=0;q<7;++q) po = FDOT2(fvh[q], wfr[q], po);
      po = half_red(po);
      float d2w = d2r + __shfl_xor(d2r, 32);
      float f2w = f2r + __shfl_xor(f2r, 32);
      if (lane==0){ atomicAdd(&d2p[kk-2], d2w); atomicAdd(&f2p[kk-2], f2w); }
      if (s==0) outk[(size_t)(kk-2)*NB + elem] = po;
    }
    slot = (slot==5)? 0 : slot+1;
  }
}

__global__ void final_kernel(const float* __restrict__ d2p, const float* __restrict__ f2p,
                             const float* __restrict__ outk, const float* __restrict__ bf,
                             float* __restrict__ out){
  int b = blockIdx.x*blockDim.x + threadIdx.x;
  float best = 1e8f; int kst = 0;
  for (int k=0;k<NITER;++k){
    float rel = sqrtf(d2p[k]) / (1e-5f + sqrtf(f2p[k]));
    if (rel < best){ best = rel; kst = k; }
  }
  out[b] = outk[(size_t)kst*NB + b] + bf[0];
}

extern "C" void kernel_launch(void* const* d_in, const int* in_sizes, int n_in,
                              void* d_out, int out_size, void* d_ws, size_t ws_size,
                              hipStream_t stream){
  const float* x  = (const float*)d_in[0];
  const float* Wh = (const float*)d_in[1];
  const float* bh = (const float*)d_in[2];
  const float* Wx = (const float*)d_in[3];
  const float* bx = (const float*)d_in[4];
  const float* Wo = (const float*)d_in[5];
  const float* bo = (const float*)d_in[6];
  const float* Wf = (const float*)d_in[7];
  const float* bf = (const float*)d_in[8];
  float* ws  = (float*)d_ws;
  float* out = (float*)d_out;

  hipLaunchKernelGGL(prep_kernel, dim3(1), dim3(256), 0, stream, Wh,bh,Wx,bx,Wo,bo,Wf,ws);
  hipLaunchKernelGGL(solver_kernel, dim3(NB/8), dim3(256), 0, stream,
                     x, ws+WS_WHP, ws+WS_BHX, ws+WS_BO,
                     (const f16x2*)(ws+WS_WX2), (const f16x2*)(ws+WS_WO2), (const f16x2*)(ws+WS_WF2),
                     ws+WS_OUTK, ws+WS_D2, ws+WS_F2);
  hipLaunchKernelGGL(final_kernel, dim3(NB/256), dim3(256), 0, stream,
                     ws+WS_D2, ws+WS_F2, ws+WS_OUTK, bf, out);
}

// Round 2
// 2877.353 us; speedup vs baseline: 1.8316x; 1.8316x over previous
//
#include <hip/hip_runtime.h>
#include <hip/hip_fp16.h>

#define S 31
#define D 14
#define H 50
#define NB 16384
#define NITER 48
#define LAMR 1e-4f

// ws float-index layout
#define WS_D2   0      // 48: global sum ||F-X||^2 per iter
#define WS_F2   64     // 48: global sum ||F||^2 per iter
#define WS_WHP  128    // 50x16 fp32 Wh (padded)
#define WS_BHX  928    // 64: bh+bx fp32
#define WS_BO   992    // 16: bo fp32
#define WS_WX2  1024   // 50x8 half2: Wx rows packed (d pairs)
#define WS_WO2  1424   // 14x26 half2: Wo rows packed (h pairs)
#define WS_WF2  1792   // 32x8 half2: Wf per-s slices (row 31 = 0)
#define WS_OUTK 4096   // 48*NB floats

typedef _Float16 f16x2 __attribute__((ext_vector_type(2)));

#if defined(__has_builtin) && __has_builtin(__builtin_amdgcn_rcpf)
#define FRCP(x) __builtin_amdgcn_rcpf(x)
#else
#define FRCP(x) (1.0f/(x))
#endif

#if defined(__has_builtin) && __has_builtin(__builtin_amdgcn_exp2f)
#define FEXP2(x) __builtin_amdgcn_exp2f(x)
#else
#define FEXP2(x) exp2f(x)
#endif

#define FDOT2(a,b,c) __builtin_amdgcn_fdot2((a),(b),(c),false)

__device__ __forceinline__ f16x2 pkrtz(float a, float b){
  auto r = __builtin_amdgcn_cvt_pkrtz(a, b);
  return __builtin_bit_cast(f16x2, r);
}
#define PKRTZ(a,b) pkrtz((a),(b))

__device__ __forceinline__ f16x2 pack_rn(float a, float b){
  __half2 h = __floats2half2_rn(a, b);
  return __builtin_bit_cast(f16x2, h);
}

// triangular index, i<=j, 6x6
#define AIJ(i,j) ((i)*6 - ((i)*((i)+1))/2 + (j))

__device__ __forceinline__ float tfast(float x){
  // tanh(x) = 1 - 2/(exp2(x*2*log2e)+1)
  float e = FEXP2(x * 2.8853900817779268f);
  return 1.f - 2.f * FRCP(e + 1.f);
}

__global__ void prep_kernel(const float* __restrict__ Wh, const float* __restrict__ bh,
                            const float* __restrict__ Wx, const float* __restrict__ bx,
                            const float* __restrict__ Wo, const float* __restrict__ bo,
                            const float* __restrict__ Wf, float* __restrict__ ws){
  int t = threadIdx.x;                       // 1 block x 256
  for (int i=t;i<128;i+=256) ws[i]=0.f;      // zero norm accumulators
  for (int i=t;i<800;i+=256){
    int h=i>>4, d=i&15;
    ws[WS_WHP+i] = (d<D)? Wh[h*D+d] : 0.f;
  }
  for (int i=t;i<64;i+=256) ws[WS_BHX+i] = (i<H)? bh[i]+bx[i] : 0.f;
  for (int i=t;i<16;i+=256) ws[WS_BO+i]  = (i<D)? bo[i] : 0.f;
  __half2* wx2 = (__half2*)(ws + WS_WX2);
  for (int i=t;i<400;i+=256){
    int h=i>>3, dd=i&7, d0=2*dd, d1=2*dd+1;
    float a=(d0<D)?Wx[h*D+d0]:0.f, b=(d1<D)?Wx[h*D+d1]:0.f;
    wx2[i] = __floats2half2_rn(a,b);
  }
  __half2* wo2 = (__half2*)(ws + WS_WO2);
  for (int i=t;i<364;i+=256){
    int d=i/26, hh=i-26*d, h0=2*hh, h1=2*hh+1;
    float a=(hh<25)?Wo[d*H+h0]:0.f, b=(hh<25)?Wo[d*H+h1]:0.f;
    wo2[i] = __floats2half2_rn(a,b);
  }
  __half2* wf2 = (__half2*)(ws + WS_WF2);
  for (int i=t;i<256;i+=256){
    int s=i>>3, dd=i&7, d0=2*dd, d1=2*dd+1;
    float a=(s<S && d0<D)?Wf[s*D+d0]:0.f, b=(s<S && d1<D)?Wf[s*D+d1]:0.f;
    wf2[i] = __floats2half2_rn(a,b);
  }
}

// f-eval, fused layers: per h-pair compute layer-1 dot + tanh, immediately
// accumulate into the 14 layer-2 fp32 chains (no thh[25] staging array).
#define FEVAL() do{ \
  float oacc_[14]; \
  _Pragma("unroll") for (int d_=0; d_<14; ++d_) oacc_[d_] = bop[d_]; \
  _Pragma("unroll") \
  for (int hh_=0; hh_<25; ++hh_){ \
    f16x2 hx2_ = hxr2[hh_]; \
    float a0_ = (float)hx2_[0], b0_ = (float)hx2_[1]; \
    _Pragma("unroll") for (int q_=0;q_<7;++q_){ \
      a0_ = FDOT2(xvh[q_], wx2[(2*hh_)*8+q_],   a0_); \
      b0_ = FDOT2(xvh[q_], wx2[(2*hh_+1)*8+q_], b0_); } \
    f16x2 th_ = PKRTZ(tfast(a0_), tfast(b0_)); \
    _Pragma("unroll") for (int d_=0; d_<14; ++d_) \
      oacc_[d_] = FDOT2(th_, wo2[d_*26+hh_], oacc_[d_]); \
  } \
  _Pragma("unroll") for (int dp_=0; dp_<7; ++dp_) \
    fvh[dp_] = PKRTZ(tfast(oacc_[2*dp_]), tfast(oacc_[2*dp_+1])); \
}while(0)

#define ZERO_INACT() do{ \
  if (!act){ \
    _Pragma("unroll") for (int q_=0;q_<7;++q_){ fvh[q_]=zzv; gvh[q_]=zzv; } \
  } \
}while(0)

// Shift-based history push (constant indices everywhere -> stays in regs).
// All 8 per-iteration 32-lane reductions (5 history dots, ||G||^2, ||F||^2,
// Wf projection) batched into ONE interleaved butterfly: 8-way ILP per level
// instead of 8 serial 5-deep shuffle chains.
#define PUSHB(DOPROJ) do{ \
  float rv_[8]; \
  _Pragma("unroll") for (int j_=0;j_<5;++j_){ \
    float acc_=0.f; \
    _Pragma("unroll") for (int q_=0;q_<7;++q_) acc_ = FDOT2(gvh[q_], Gh[(j_+1)*7+q_], acc_); \
    rv_[j_] = acc_; } \
  d2l=0.f; f2l=0.f; \
  _Pragma("unroll") for (int q_=0;q_<7;++q_){ \
    d2l = FDOT2(gvh[q_], gvh[q_], d2l); \
    f2l = FDOT2(fvh[q_], fvh[q_], f2l); } \
  rv_[5]=d2l; rv_[6]=f2l; rv_[7]=0.f; \
  if (DOPROJ){ \
    float pa_=0.f; \
    _Pragma("unroll") for (int q_=0;q_<7;++q_) pa_ = FDOT2(fvh[q_], wfr[q_], pa_); \
    rv_[7]=pa_; } \
  _Pragma("unroll") for (int m_=1;m_<32;m_<<=1) \
    _Pragma("unroll") for (int i_=0;i_<8;++i_) rv_[i_] += __shfl_xor(rv_[i_], m_); \
  d2r = rv_[5]; f2r = rv_[6]; po_red = rv_[7]; \
  _Pragma("unroll") for (int j_=0;j_<5;++j_) \
    _Pragma("unroll") for (int q_=0;q_<7;++q_){ \
      Fh[j_*7+q_] = Fh[(j_+1)*7+q_]; Gh[j_*7+q_] = Gh[(j_+1)*7+q_]; } \
  _Pragma("unroll") for (int q_=0;q_<7;++q_){ Fh[35+q_]=fvh[q_]; Gh[35+q_]=gvh[q_]; } \
  _Pragma("unroll") for (int i_=0;i_<5;++i_) \
    _Pragma("unroll") for (int j_=i_;j_<5;++j_) GG[AIJ(i_,j_)] = GG[AIJ(i_+1,j_+1)]; \
  _Pragma("unroll") for (int j_=0;j_<5;++j_) GG[AIJ(j_,5)] = rv_[j_]; \
  GG[AIJ(5,5)] = d2r; \
}while(0)

__global__ __launch_bounds__(256, 3)
void solver_kernel(const float* __restrict__ x,
                   const float* __restrict__ whp, const float* __restrict__ bhx,
                   const float* __restrict__ bop,
                   const f16x2* __restrict__ wx2, const f16x2* __restrict__ wo2,
                   const f16x2* __restrict__ wf2,
                   float* __restrict__ outk, float* __restrict__ d2p, float* __restrict__ f2p){
  const int tid  = threadIdx.x;
  const int lane = tid & 63;
  const int s    = tid & 31;
  const int elem = blockIdx.x*8 + (tid>>5);
  const bool act = (s < S);

  // hx as f16x2, stride 27 words (odd -> all-bank spread, 2-way max = free)
  __shared__ f16x2 hx2_sh[256*27];          // 27648 B
  f16x2* hxw2 = hx2_sh + tid*27;

  { // prologue: hx[h] = x_s . Wh_h + bh_h + bx_h  (fp32, one RNE round to fp16)
    float xd[D];
#pragma unroll
    for (int d=0; d<D; ++d) xd[d]=0.f;
    if (act){
      const float* xr = x + ((size_t)elem*S + s)*D;
#pragma unroll
      for (int d=0; d<D; ++d) xd[d]=xr[d];
    }
#pragma unroll 5
    for (int hp=0; hp<25; ++hp){
      float a0 = bhx[2*hp], a1 = bhx[2*hp+1];
#pragma unroll
      for (int d=0; d<D; ++d){
        a0 += xd[d]*whp[(2*hp)*16+d];
        a1 += xd[d]*whp[(2*hp+1)*16+d];
      }
      hxw2[hp] = pack_rn(a0, a1);
    }
  }
  const f16x2* hxr2 = hxw2;
  const f16x2 zzv = {(_Float16)0.f, (_Float16)0.f};
  const f16x2* wfr = wf2 + s*8;

  f16x2 Fh[42], Gh[42], xvh[7], fvh[7], gvh[7];
  float GG[21];
  float d2l, f2l, d2r, f2r, po_red;
#pragma unroll
  for (int i=0;i<42;++i){ Fh[i]=zzv; Gh[i]=zzv; }
#pragma unroll
  for (int i=0;i<21;++i) GG[i]=0.f;

  // init entry 0: X0=0, F0=f(0)
#pragma unroll
  for (int q=0;q<7;++q) xvh[q]=zzv;
  FEVAL();
#pragma unroll
  for (int q=0;q<7;++q) gvh[q]=fvh[q]-xvh[q];
  ZERO_INACT();
  PUSHB(0);
  // init entry 1: X1=F0, F1=f(F0)
#pragma unroll
  for (int q=0;q<7;++q) xvh[q]=fvh[q];
  FEVAL();
#pragma unroll
  for (int q=0;q<7;++q) gvh[q]=fvh[q]-xvh[q];
  ZERO_INACT();
  PUSHB(0);

#pragma unroll 1
  for (int kk=2; kk<50; ++kk){
    float A_[21], invd[6], yv[6];
    if (kk >= 6){
#pragma unroll
      for (int i=0;i<6;++i)
#pragma unroll
        for (int j=i;j<6;++j) A_[AIJ(i,j)] = GG[AIJ(i,j)] + ((i==j)?LAMR:0.f);
    } else {
      int lo = 6-kk;
#pragma unroll
      for (int i=0;i<6;++i)
#pragma unroll
        for (int j=i;j<6;++j){
          float v = GG[AIJ(i,j)] + ((i==j)?LAMR:0.f);
          A_[AIJ(i,j)] = (i>=lo)? v : ((i==j)?1e30f:0.f);
        }
    }
#pragma unroll
    for (int i=0;i<6;++i) yv[i]=1.f;
    // symmetric GE (no pivoting; SPD + big-diag pads)
#pragma unroll
    for (int p=0;p<6;++p){
      invd[p] = FRCP(A_[AIJ(p,p)]);
#pragma unroll
      for (int i=p+1;i<6;++i){
        float m = A_[AIJ(p,i)]*invd[p];
#pragma unroll
        for (int j=i;j<6;++j) A_[AIJ(i,j)] -= m*A_[AIJ(p,j)];
        yv[i] -= m*yv[p];
      }
    }
#pragma unroll
    for (int p=5;p>=0;--p){
      float acc=yv[p];
#pragma unroll
      for (int j=p+1;j<6;++j) acc -= A_[AIJ(p,j)]*yv[j];
      yv[p]=acc*invd[p];
    }
    float isum = FRCP(yv[0]+yv[1]+yv[2]+yv[3]+yv[4]+yv[5]);
    // Xk = sum_j alpha_j F_j  (fp16 packed)
#pragma unroll
    for (int q=0;q<7;++q) xvh[q]=zzv;
#pragma unroll
    for (int j=0;j<6;++j){
      _Float16 ah = (_Float16)(yv[j]*isum);
      f16x2 a2 = {ah, ah};
#pragma unroll
      for (int q=0;q<7;++q) xvh[q] += a2*Fh[j*7+q];
    }
    FEVAL();
#pragma unroll
    for (int q=0;q<7;++q) gvh[q]=fvh[q]-xvh[q];
    ZERO_INACT();
    PUSHB(1);
    float d2w = d2r + __shfl_xor(d2r, 32);
    float f2w = f2r + __shfl_xor(f2r, 32);
    if (lane==0){ atomicAdd(&d2p[kk-2], d2w); atomicAdd(&f2p[kk-2], f2w); }
    if (s==0) outk[(size_t)(kk-2)*NB + elem] = po_red;
  }
}

__global__ void final_kernel(const float* __restrict__ d2p, const float* __restrict__ f2p,
                             const float* __restrict__ outk, const float* __restrict__ bf,
                             float* __restrict__ out){
  int b = blockIdx.x*blockDim.x + threadIdx.x;
  float best = 1e8f; int kst = 0;
  for (int k=0;k<NITER;++k){
    float rel = sqrtf(d2p[k]) / (1e-5f + sqrtf(f2p[k]));
    if (rel < best){ best = rel; kst = k; }
  }
  out[b] = outk[(size_t)kst*NB + b] + bf[0];
}

extern "C" void kernel_launch(void* const* d_in, const int* in_sizes, int n_in,
                              void* d_out, int out_size, void* d_ws, size_t ws_size,
                              hipStream_t stream){
  const float* x  = (const float*)d_in[0];
  const float* Wh = (const float*)d_in[1];
  const float* bh = (const float*)d_in[2];
  const float* Wx = (const float*)d_in[3];
  const float* bx = (const float*)d_in[4];
  const float* Wo = (const float*)d_in[5];
  const float* bo = (const float*)d_in[6];
  const float* Wf = (const float*)d_in[7];
  const float* bf = (const float*)d_in[8];
  float* ws  = (float*)d_ws;
  float* out = (float*)d_out;

  hipLaunchKernelGGL(prep_kernel, dim3(1), dim3(256), 0, stream, Wh,bh,Wx,bx,Wo,bo,Wf,ws);
  hipLaunchKernelGGL(solver_kernel, dim3(NB/8), dim3(256), 0, stream,
                     x, ws+WS_WHP, ws+WS_BHX, ws+WS_BO,
                     (const f16x2*)(ws+WS_WX2), (const f16x2*)(ws+WS_WO2), (const f16x2*)(ws+WS_WF2),
                     ws+WS_OUTK, ws+WS_D2, ws+WS_F2);
  hipLaunchKernelGGL(final_kernel, dim3(NB/256), dim3(256), 0, stream,
                     ws+WS_D2, ws+WS_F2, ws+WS_OUTK, bf, out);
}